// Round 1
// baseline (821.399 us; speedup 1.0000x reference)
//
#include <hip/hip_runtime.h>
#include <hip/hip_bf16.h>

// dims (fixed): T=4, B=1024, WH=WW=8, C=256, NH=8, HD=32
// tokens per timestep G = B*64 = 65536 ; plane = G*256 = 16777216 elements
static constexpr int  G     = 65536;
static constexpr long PLANE = 16777216L;

__device__ __forceinline__ float bfh(unsigned short u) {
    union { unsigned u32; float f; } c; c.u32 = ((unsigned)u) << 16; return c.f;
}

// ---------------- prep: transposed weights into workspace + flag clear --------
__global__ void prep_kernel(const float* __restrict__ Wq, const float* __restrict__ Wk,
                            const float* __restrict__ Wp,
                            __hip_bfloat16* __restrict__ WqT, __hip_bfloat16* __restrict__ WkT,
                            float* __restrict__ WpT, unsigned* __restrict__ flag)
{
    int c = blockIdx.x;      // input channel (row of transposed)
    int j = threadIdx.x;     // output channel
    int idx = c * 256 + j;
    WqT[idx] = __float2bfloat16(Wq[j * 256 + c]);
    WkT[idx] = __float2bfloat16(Wk[j * 256 + c]);
    WpT[idx] = Wp[j * 256 + c];
    if (c == 0 && j == 0) *flag = 0u;
}

// depth-2 pipelined sparse row-gather over one 64-bit mask word (rare k-path)
__device__ __forceinline__ void gather_word(unsigned long long mm, int j, int lane,
                                            const __hip_bfloat16* __restrict__ WT,
                                            float& q0, float& q1, float& q2, float& q3)
{
    if (!mm) return;
    int b = __ffsll(mm) - 1; mm &= (mm - 1);
    ushort4 w = *((const ushort4*)(WT + (4 * b + j) * 256 + 4 * lane));
    while (mm) {
        int b2 = __ffsll(mm) - 1; mm &= (mm - 1);
        ushort4 w2 = *((const ushort4*)(WT + (4 * b2 + j) * 256 + 4 * lane));
        q0 += bfh(w.x); q1 += bfh(w.y); q2 += bfh(w.z); q3 += bfh(w.w);
        w = w2;
    }
    q0 += bfh(w.x); q1 += bfh(w.y); q2 += bfh(w.z); q3 += bfh(w.w);
}

// 8 independent chains (2 timesteps x 4 words): up to 8 loads in flight/iter.
// Masks are wave-uniform (ballot results) -> guards are cheap scalar branches.
__device__ __forceinline__ void gather8(
    unsigned long long m0, unsigned long long m1, unsigned long long m2, unsigned long long m3,
    unsigned long long n0, unsigned long long n1, unsigned long long n2, unsigned long long n3,
    const __hip_bfloat16* __restrict__ WT, int lane,
    float4& qa, float4& qb)
{
    const __hip_bfloat16* base = WT + 4 * lane;
    ushort4 w0 = {0,0,0,0}, w1 = {0,0,0,0}, w2 = {0,0,0,0}, w3 = {0,0,0,0};
    ushort4 x0 = {0,0,0,0}, x1 = {0,0,0,0}, x2 = {0,0,0,0}, x3 = {0,0,0,0};
    while (m0 | m1 | m2 | m3 | n0 | n1 | n2 | n3) {
        bool h0 = m0 != 0, h1 = m1 != 0, h2 = m2 != 0, h3 = m3 != 0;
        bool g0 = n0 != 0, g1 = n1 != 0, g2 = n2 != 0, g3 = n3 != 0;
        if (h0) { int b = __ffsll(m0) - 1; m0 &= m0 - 1; w0 = *(const ushort4*)(base + (4*b+0)*256); }
        if (h1) { int b = __ffsll(m1) - 1; m1 &= m1 - 1; w1 = *(const ushort4*)(base + (4*b+1)*256); }
        if (h2) { int b = __ffsll(m2) - 1; m2 &= m2 - 1; w2 = *(const ushort4*)(base + (4*b+2)*256); }
        if (h3) { int b = __ffsll(m3) - 1; m3 &= m3 - 1; w3 = *(const ushort4*)(base + (4*b+3)*256); }
        if (g0) { int b = __ffsll(n0) - 1; n0 &= n0 - 1; x0 = *(const ushort4*)(base + (4*b+0)*256); }
        if (g1) { int b = __ffsll(n1) - 1; n1 &= n1 - 1; x1 = *(const ushort4*)(base + (4*b+1)*256); }
        if (g2) { int b = __ffsll(n2) - 1; n2 &= n2 - 1; x2 = *(const ushort4*)(base + (4*b+2)*256); }
        if (g3) { int b = __ffsll(n3) - 1; n3 &= n3 - 1; x3 = *(const ushort4*)(base + (4*b+3)*256); }
        if (h0) { qa.x += bfh(w0.x); qa.y += bfh(w0.y); qa.z += bfh(w0.z); qa.w += bfh(w0.w); }
        if (h1) { qa.x += bfh(w1.x); qa.y += bfh(w1.y); qa.z += bfh(w1.z); qa.w += bfh(w1.w); }
        if (h2) { qa.x += bfh(w2.x); qa.y += bfh(w2.y); qa.z += bfh(w2.z); qa.w += bfh(w2.w); }
        if (h3) { qa.x += bfh(w3.x); qa.y += bfh(w3.y); qa.z += bfh(w3.z); qa.w += bfh(w3.w); }
        if (g0) { qb.x += bfh(x0.x); qb.y += bfh(x0.y); qb.z += bfh(x0.z); qb.w += bfh(x0.w); }
        if (g1) { qb.x += bfh(x1.x); qb.y += bfh(x1.y); qb.z += bfh(x1.z); qb.w += bfh(x1.w); }
        if (g2) { qb.x += bfh(x2.x); qb.y += bfh(x2.y); qb.z += bfh(x2.z); qb.w += bfh(x2.w); }
        if (g3) { qb.x += bfh(x3.x); qb.y += bfh(x3.y); qb.z += bfh(x3.z); qb.w += bfh(x3.w); }
    }
}

// ---------------- fused: LIF(x) -> sparse q-GEMM -> LIF -> att -> AM masks ----
// NEW: speculative output stores. attn_out == 0 unconditionally (proved R0:
// x2 in {0,1} => membrane (v+x)/2 < 1 strictly). y == bp whenever this token's
// att never spikes. So each wave stores its token's 8 output rows (y=bp,
// attn_out=0) up front -- fire-and-forget stores that drain under the gather's
// latency stalls. In the rare flag!=0 case, out_kernel rewrites EVERY y row
// (kernel-boundary ordering on the same stream), so speculation is safe.
__global__ __launch_bounds__(256) void lif_qk_kernel(
    const float* __restrict__ x,
    unsigned* __restrict__ AM,
    const __hip_bfloat16* __restrict__ WqT,
    const __hip_bfloat16* __restrict__ WkT,
    const float* __restrict__ pos,
    const float* __restrict__ bp,
    float* __restrict__ y,
    float* __restrict__ attn_out,
    unsigned* __restrict__ flag)
{
    int lane = threadIdx.x & 63;
    int wv   = threadIdx.x >> 6;
    int wid  = blockIdx.x * 4 + wv;       // 16384 waves
    int sh   = (lane & 56);               // 8*(lane>>3)

    float4 base = ((const float4*)bp)[lane];
    const float4 z4 = make_float4(0.f, 0.f, 0.f, 0.f);

    for (int gi = 0; gi < 4; ++gi) {
        int g  = wid * 4 + gi;            // token 0..65535
        int hw = g & 63;
        int b  = g >> 6;

        float4 X[4];
        #pragma unroll
        for (int t = 0; t < 4; ++t)
            X[t] = ((const float4*)(x + (long)t * PLANE + (long)g * 256))[lane];

        // speculative constant outputs for this token (overlap with X loads
        // in flight and the gather latency below; no data dependency)
        #pragma unroll
        for (int t = 0; t < 4; ++t)
            ((float4*)y)[((long)b * 256 + t * 64 + hw) * 64 + lane] = base;
        #pragma unroll
        for (int t = 0; t < 4; ++t)
            ((float4*)attn_out)[((long)t * G + g) * 64 + lane] = z4;

        // phase 1: all 16 input-spike mask words (pure VALU + ballots)
        unsigned long long sm[4][4];
        float4 v = make_float4(0.f, 0.f, 0.f, 0.f);
        #pragma unroll
        for (int t = 0; t < 4; ++t) {
            v.x = v.x + (X[t].x - v.x) * 0.5f; bool s0 = (v.x - 1.0f) >= 0.0f; if (s0) v.x = 0.f;
            v.y = v.y + (X[t].y - v.y) * 0.5f; bool s1 = (v.y - 1.0f) >= 0.0f; if (s1) v.y = 0.f;
            v.z = v.z + (X[t].z - v.z) * 0.5f; bool s2 = (v.z - 1.0f) >= 0.0f; if (s2) v.z = 0.f;
            v.w = v.w + (X[t].w - v.w) * 0.5f; bool s3 = (v.w - 1.0f) >= 0.0f; if (s3) v.w = 0.f;
            sm[t][0] = __ballot(s0);
            sm[t][1] = __ballot(s1);
            sm[t][2] = __ballot(s2);
            sm[t][3] = __ballot(s3);
        }

        // phase 2: sparse q gathers, 8 chains in flight
        float4 qs0 = make_float4(0.f,0.f,0.f,0.f), qs1 = make_float4(0.f,0.f,0.f,0.f);
        float4 qs2 = make_float4(0.f,0.f,0.f,0.f), qs3 = make_float4(0.f,0.f,0.f,0.f);
        gather8(sm[0][0], sm[0][1], sm[0][2], sm[0][3],
                sm[1][0], sm[1][1], sm[1][2], sm[1][3], WqT, lane, qs0, qs1);
        gather8(sm[2][0], sm[2][1], sm[2][2], sm[2][3],
                sm[3][0], sm[3][1], sm[3][2], sm[3][3], WqT, lane, qs2, qs3);

        // phase 3: q LIF + att-token LIF (identical arithmetic to prior rounds)
        float4 vq = make_float4(0.f, 0.f, 0.f, 0.f);
        float  va = 0.f;
        unsigned attb = 0u;
        #pragma unroll
        for (int t = 0; t < 4; ++t) {
            float4 q = (t == 0) ? qs0 : (t == 1) ? qs1 : (t == 2) ? qs2 : qs3;
            vq.x = vq.x + (q.x - vq.x) * 0.5f; bool t0 = (vq.x - 1.0f) >= 0.0f; if (t0) vq.x = 0.f;
            vq.y = vq.y + (q.y - vq.y) * 0.5f; bool t1 = (vq.y - 1.0f) >= 0.0f; if (t1) vq.y = 0.f;
            vq.z = vq.z + (q.z - vq.z) * 0.5f; bool t2 = (vq.z - 1.0f) >= 0.0f; if (t2) vq.z = 0.f;
            vq.w = vq.w + (q.w - vq.w) * 0.5f; bool t3 = (vq.w - 1.0f) >= 0.0f; if (t3) vq.w = 0.f;
            unsigned long long qb0 = __ballot(t0);
            unsigned long long qb1 = __ballot(t1);
            unsigned long long qb2 = __ballot(t2);
            unsigned long long qb3 = __ballot(t3);

            int cnt = __popc((unsigned)((qb0 >> sh) & 0xFFull))
                    + __popc((unsigned)((qb1 >> sh) & 0xFFull))
                    + __popc((unsigned)((qb2 >> sh) & 0xFFull))
                    + __popc((unsigned)((qb3 >> sh) & 0xFFull));
            va = va + ((float)cnt - va) * 0.5f;
            bool a = (va - 1.0f) >= 0.0f; if (a) va = 0.f;
            attb |= (a ? 1u : 0u) << t;
        }

        bool anyatt = (__ballot(attb != 0u) != 0ull);
        if (!anyatt) {
            if (lane < 32) {
                int t = lane >> 3, wd = lane & 7;
                AM[((long)t * G + g) * 8 + wd] = 0u;
            }
        } else {
            // rare: full k path (wave-uniform)
            if (lane == 0) atomicOr(flag, 1u);
            float4 vk = make_float4(0.f, 0.f, 0.f, 0.f);
            #pragma unroll
            for (int t = 0; t < 4; ++t) {
                float k0 = 0.f, k1 = 0.f, k2 = 0.f, k3 = 0.f;
                #pragma unroll
                for (int j = 0; j < 4; ++j)
                    gather_word(sm[t][j], j, lane, WkT, k0, k1, k2, k3);
                float4 pp = ((const float4*)(pos + t * 16384 + hw * 256))[lane];
                k0 += pp.x; k1 += pp.y; k2 += pp.z; k3 += pp.w;

                vk.x = vk.x + (k0 - vk.x) * 0.5f; bool t0 = (vk.x - 1.0f) >= 0.0f; if (t0) vk.x = 0.f;
                vk.y = vk.y + (k1 - vk.y) * 0.5f; bool t1 = (vk.y - 1.0f) >= 0.0f; if (t1) vk.y = 0.f;
                vk.z = vk.z + (k2 - vk.z) * 0.5f; bool t2 = (vk.z - 1.0f) >= 0.0f; if (t2) vk.z = 0.f;
                vk.w = vk.w + (k3 - vk.w) * 0.5f; bool t3 = (vk.w - 1.0f) >= 0.0f; if (t3) vk.w = 0.f;

                bool at = ((attb >> t) & 1u) != 0u;
                unsigned long long bb[4];
                bb[0] = __ballot(t0 && at);
                bb[1] = __ballot(t1 && at);
                bb[2] = __ballot(t2 && at);
                bb[3] = __ballot(t3 && at);
                if (lane < 8) {
                    unsigned wdv = 0u;
                    #pragma unroll
                    for (int hd = 0; hd < 32; ++hd) {
                        int ls = lane * 8 + (hd >> 2);
                        wdv |= (unsigned)((bb[hd & 3] >> ls) & 1ull) << hd;
                    }
                    AM[((long)t * G + g) * 8 + lane] = wdv;
                }
            }
        }
    }
}

// ---------------- out: flag-gated; common case is now a no-op ----------------
// Common case (flag==0): lif_qk already stored y = bp and attn_out = 0 -> return.
// Rare case: per-row AM gather (permutation verified R0) rewrites EVERY row,
// overwriting the speculative stores (kernel-boundary ordering guarantees
// visibility). attn_out ≡ 0 always (proof in lif_qk header comment).
__global__ __launch_bounds__(256) void out_kernel(
    const unsigned* __restrict__ AM,
    const float* __restrict__ WpT,
    const float* __restrict__ bp,
    const unsigned* __restrict__ flag,
    float* __restrict__ y,
    float* __restrict__ attn_out)
{
    if (*flag == 0u) return;

    int lane = threadIdx.x & 63;
    int wv   = threadIdx.x >> 6;
    long wave = (long)blockIdx.x * 4 + wv;      // 0..8191 ; 32 rows/wave
    int  nh   = lane >> 3;

    float4 base = ((const float4*)bp)[lane];
    const float4 z = make_float4(0.f, 0.f, 0.f, 0.f);
    long row0 = wave * 32;

    // rare path
    int t2  = (int)(row0 >> 16);
    int b2  = (int)(row0 >> 6) & 1023;
    int hw2 = (int)row0 & 63;
    int srow = (b2 * 4 + (nh >> 1)) * 64 + (nh & 1) * 32 + t2 * 8 + (hw2 >> 3);
    unsigned W = AM[(long)srow * 8 + (hw2 & 7)];

    for (int r = 0; r < 32; ++r) {
        long row = row0 + r;
        unsigned Wn = 0u;
        if (r < 31) {
            long rown = row + 1;
            int t2n  = (int)(rown >> 16);
            int b2n  = (int)(rown >> 6) & 1023;
            int hw2n = (int)rown & 63;
            int srn  = (b2n * 4 + (nh >> 1)) * 64 + (nh & 1) * 32 + t2n * 8 + (hw2n >> 3);
            Wn = AM[(long)srn * 8 + (hw2n & 7)];
        }
        float4 val = base;
        if (__ballot(W != 0u) != 0ull) {
            #pragma unroll 1
            for (int n2 = 0; n2 < 8; ++n2) {
                unsigned Wx = __shfl(W, n2 * 8);
                while (Wx) {
                    int hd = __ffs(Wx) - 1;
                    Wx &= (Wx - 1);
                    float4 wl = ((const float4*)(WpT + (n2 * 32 + hd) * 256))[lane];
                    val.x += wl.x; val.y += wl.y; val.z += wl.z; val.w += wl.w;
                }
            }
        }
        ((float4*)y)[row * 64 + lane]        = val;
        ((float4*)attn_out)[row * 64 + lane] = z;
        W = Wn;
    }
}

extern "C" void kernel_launch(void* const* d_in, const int* in_sizes, int n_in,
                              void* d_out, int out_size, void* d_ws, size_t ws_size,
                              hipStream_t stream) {
    const float* x   = (const float*)d_in[0];
    const float* Wq  = (const float*)d_in[1];
    const float* Wk  = (const float*)d_in[2];
    const float* Wp  = (const float*)d_in[3];
    const float* bp  = (const float*)d_in[4];
    const float* pos = (const float*)d_in[5];

    float* y        = (float*)d_out;
    float* attn_out = y + 67108864L;

    char* ws = (char*)d_ws;
    unsigned*           AM   = (unsigned*)(ws);
    __hip_bfloat16*     WqT  = (__hip_bfloat16*)(ws + (8L << 20));
    __hip_bfloat16*     WkT  = (__hip_bfloat16*)(ws + (8L << 20) + (128L << 10));
    float*              WpT  = (float*)(ws + (8L << 20) + (256L << 10));
    unsigned*           flag = (unsigned*)(ws + (8L << 20) + (512L << 10));

    prep_kernel<<<256, 256, 0, stream>>>(Wq, Wk, Wp, WqT, WkT, WpT, flag);
    lif_qk_kernel<<<4096, 256, 0, stream>>>(x, AM, WqT, WkT, pos, bp, y, attn_out, flag);
    out_kernel<<<2048, 256, 0, stream>>>(AM, WpT, bp, flag, y, attn_out);
}

// Round 2
// 784.123 us; speedup vs baseline: 1.0475x; 1.0475x over previous
//
#include <hip/hip_runtime.h>
#include <hip/hip_bf16.h>

// dims (fixed): T=4, B=1024, WH=WW=8, C=256, NH=8, HD=32
// tokens per timestep G = B*64 = 65536 ; plane = G*256 = 16777216 elements
static constexpr int  G     = 65536;
static constexpr long PLANE = 16777216L;

__device__ __forceinline__ float bfh(unsigned short u) {
    union { unsigned u32; float f; } c; c.u32 = ((unsigned)u) << 16; return c.f;
}

// ---------------- prep: transposed weights into workspace + flag clear --------
__global__ void prep_kernel(const float* __restrict__ Wq, const float* __restrict__ Wk,
                            const float* __restrict__ Wp,
                            __hip_bfloat16* __restrict__ WqT, __hip_bfloat16* __restrict__ WkT,
                            float* __restrict__ WpT, unsigned* __restrict__ flag)
{
    int c = blockIdx.x;      // input channel (row of transposed)
    int j = threadIdx.x;     // output channel
    int idx = c * 256 + j;
    WqT[idx] = __float2bfloat16(Wq[j * 256 + c]);
    WkT[idx] = __float2bfloat16(Wk[j * 256 + c]);
    WpT[idx] = Wp[j * 256 + c];
    if (c == 0 && j == 0) *flag = 0u;
}

// depth-2 pipelined sparse row-gather over one 64-bit mask word (rare k-path)
__device__ __forceinline__ void gather_word(unsigned long long mm, int j, int lane,
                                            const __hip_bfloat16* __restrict__ WT,
                                            float& q0, float& q1, float& q2, float& q3)
{
    if (!mm) return;
    int b = __ffsll(mm) - 1; mm &= (mm - 1);
    ushort4 w = *((const ushort4*)(WT + (4 * b + j) * 256 + 4 * lane));
    while (mm) {
        int b2 = __ffsll(mm) - 1; mm &= (mm - 1);
        ushort4 w2 = *((const ushort4*)(WT + (4 * b2 + j) * 256 + 4 * lane));
        q0 += bfh(w.x); q1 += bfh(w.y); q2 += bfh(w.z); q3 += bfh(w.w);
        w = w2;
    }
    q0 += bfh(w.x); q1 += bfh(w.y); q2 += bfh(w.z); q3 += bfh(w.w);
}

// 8 chains x depth-2 software pipeline: trip i+1's loads are issued BEFORE
// trip i's accumulates, so up to 16 loads are in flight and the ~250-cycle
// L2 trip latency is hidden under the ~128-cycle accumulate of the previous
// trip. Masks are wave-uniform (ballot results) -> all guards are scalar.
__device__ __forceinline__ void gather8(
    unsigned long long m0, unsigned long long m1, unsigned long long m2, unsigned long long m3,
    unsigned long long n0, unsigned long long n1, unsigned long long n2, unsigned long long n3,
    const __hip_bfloat16* __restrict__ WT, int lane,
    float4& qa, float4& qb)
{
    const __hip_bfloat16* base = WT + 4 * lane;
    ushort4 w0 = {0,0,0,0}, w1 = {0,0,0,0}, w2 = {0,0,0,0}, w3 = {0,0,0,0};
    ushort4 x0 = {0,0,0,0}, x1 = {0,0,0,0}, x2 = {0,0,0,0}, x3 = {0,0,0,0};
    bool p0 = false, p1 = false, p2 = false, p3 = false;
    bool r0 = false, r1 = false, r2 = false, r3 = false;

    // prologue: issue first batch
    if (m0) { int b = __ffsll(m0) - 1; m0 &= m0 - 1; w0 = *(const ushort4*)(base + (4*b+0)*256); p0 = true; }
    if (m1) { int b = __ffsll(m1) - 1; m1 &= m1 - 1; w1 = *(const ushort4*)(base + (4*b+1)*256); p1 = true; }
    if (m2) { int b = __ffsll(m2) - 1; m2 &= m2 - 1; w2 = *(const ushort4*)(base + (4*b+2)*256); p2 = true; }
    if (m3) { int b = __ffsll(m3) - 1; m3 &= m3 - 1; w3 = *(const ushort4*)(base + (4*b+3)*256); p3 = true; }
    if (n0) { int b = __ffsll(n0) - 1; n0 &= n0 - 1; x0 = *(const ushort4*)(base + (4*b+0)*256); r0 = true; }
    if (n1) { int b = __ffsll(n1) - 1; n1 &= n1 - 1; x1 = *(const ushort4*)(base + (4*b+1)*256); r1 = true; }
    if (n2) { int b = __ffsll(n2) - 1; n2 &= n2 - 1; x2 = *(const ushort4*)(base + (4*b+2)*256); r2 = true; }
    if (n3) { int b = __ffsll(n3) - 1; n3 &= n3 - 1; x3 = *(const ushort4*)(base + (4*b+3)*256); r3 = true; }

    while (p0 | p1 | p2 | p3 | r0 | r1 | r2 | r3) {
        // issue next batch first (stays in flight while we accumulate current)
        ushort4 v0 = {0,0,0,0}, v1 = {0,0,0,0}, v2 = {0,0,0,0}, v3 = {0,0,0,0};
        ushort4 u0 = {0,0,0,0}, u1 = {0,0,0,0}, u2 = {0,0,0,0}, u3 = {0,0,0,0};
        bool c0 = false, c1 = false, c2 = false, c3 = false;
        bool d0 = false, d1 = false, d2 = false, d3 = false;
        if (m0) { int b = __ffsll(m0) - 1; m0 &= m0 - 1; v0 = *(const ushort4*)(base + (4*b+0)*256); c0 = true; }
        if (m1) { int b = __ffsll(m1) - 1; m1 &= m1 - 1; v1 = *(const ushort4*)(base + (4*b+1)*256); c1 = true; }
        if (m2) { int b = __ffsll(m2) - 1; m2 &= m2 - 1; v2 = *(const ushort4*)(base + (4*b+2)*256); c2 = true; }
        if (m3) { int b = __ffsll(m3) - 1; m3 &= m3 - 1; v3 = *(const ushort4*)(base + (4*b+3)*256); c3 = true; }
        if (n0) { int b = __ffsll(n0) - 1; n0 &= n0 - 1; u0 = *(const ushort4*)(base + (4*b+0)*256); d0 = true; }
        if (n1) { int b = __ffsll(n1) - 1; n1 &= n1 - 1; u1 = *(const ushort4*)(base + (4*b+1)*256); d1 = true; }
        if (n2) { int b = __ffsll(n2) - 1; n2 &= n2 - 1; u2 = *(const ushort4*)(base + (4*b+2)*256); d2 = true; }
        if (n3) { int b = __ffsll(n3) - 1; n3 &= n3 - 1; u3 = *(const ushort4*)(base + (4*b+3)*256); d3 = true; }

        // accumulate current batch (loads issued one trip ago)
        if (p0) { qa.x += bfh(w0.x); qa.y += bfh(w0.y); qa.z += bfh(w0.z); qa.w += bfh(w0.w); }
        if (p1) { qa.x += bfh(w1.x); qa.y += bfh(w1.y); qa.z += bfh(w1.z); qa.w += bfh(w1.w); }
        if (p2) { qa.x += bfh(w2.x); qa.y += bfh(w2.y); qa.z += bfh(w2.z); qa.w += bfh(w2.w); }
        if (p3) { qa.x += bfh(w3.x); qa.y += bfh(w3.y); qa.z += bfh(w3.z); qa.w += bfh(w3.w); }
        if (r0) { qb.x += bfh(x0.x); qb.y += bfh(x0.y); qb.z += bfh(x0.z); qb.w += bfh(x0.w); }
        if (r1) { qb.x += bfh(x1.x); qb.y += bfh(x1.y); qb.z += bfh(x1.z); qb.w += bfh(x1.w); }
        if (r2) { qb.x += bfh(x2.x); qb.y += bfh(x2.y); qb.z += bfh(x2.z); qb.w += bfh(x2.w); }
        if (r3) { qb.x += bfh(x3.x); qb.y += bfh(x3.y); qb.z += bfh(x3.z); qb.w += bfh(x3.w); }

        w0 = v0; w1 = v1; w2 = v2; w3 = v3;
        x0 = u0; x1 = u1; x2 = u2; x3 = u3;
        p0 = c0; p1 = c1; p2 = c2; p3 = c3;
        r0 = d0; r1 = d1; r2 = d2; r3 = d3;
    }
}

// ---------------- fused: LIF(x) -> sparse q-GEMM -> LIF -> att -> AM masks ----
// Lane holds channels 4*lane..4*lane+3. Ballot word j bit lane = spike(4*lane+j).
// Bit-exact LIF: v = v + (x-v)*0.5, spike = (v-1 >= 0), hard reset.
// R2: depth-2 pipelined gathers + next-token X prefetch issued before the
// gather phase (HBM latency hides under ~2000 cyc of gather work).
// R1's speculative y/attn stores REVERTED: stores share the in-order vmcnt
// queue with gather loads -> every gather waitcnt also drained HBM store
// traffic (+115 us measured). Stores live in out_kernel again.
__global__ __launch_bounds__(256) void lif_qk_kernel(
    const float* __restrict__ x,
    unsigned* __restrict__ AM,
    const __hip_bfloat16* __restrict__ WqT,
    const __hip_bfloat16* __restrict__ WkT,
    const float* __restrict__ pos,
    unsigned* __restrict__ flag)
{
    int lane = threadIdx.x & 63;
    int wv   = threadIdx.x >> 6;
    int wid  = blockIdx.x * 4 + wv;       // 16384 waves
    int sh   = (lane & 56);               // 8*(lane>>3)

    float4 X[4];
    #pragma unroll
    for (int t = 0; t < 4; ++t)
        X[t] = ((const float4*)(x + (long)t * PLANE + (long)(wid * 4) * 256))[lane];

    for (int gi = 0; gi < 4; ++gi) {
        int g  = wid * 4 + gi;            // token 0..65535
        int hw = g & 63;

        // phase 1: all 16 input-spike mask words (pure VALU + ballots)
        unsigned long long sm[4][4];
        float4 v = make_float4(0.f, 0.f, 0.f, 0.f);
        #pragma unroll
        for (int t = 0; t < 4; ++t) {
            v.x = v.x + (X[t].x - v.x) * 0.5f; bool s0 = (v.x - 1.0f) >= 0.0f; if (s0) v.x = 0.f;
            v.y = v.y + (X[t].y - v.y) * 0.5f; bool s1 = (v.y - 1.0f) >= 0.0f; if (s1) v.y = 0.f;
            v.z = v.z + (X[t].z - v.z) * 0.5f; bool s2 = (v.z - 1.0f) >= 0.0f; if (s2) v.z = 0.f;
            v.w = v.w + (X[t].w - v.w) * 0.5f; bool s3 = (v.w - 1.0f) >= 0.0f; if (s3) v.w = 0.f;
            sm[t][0] = __ballot(s0);
            sm[t][1] = __ballot(s1);
            sm[t][2] = __ballot(s2);
            sm[t][3] = __ballot(s3);
        }

        // prefetch next token's X: issued now, consumed after the gathers
        float4 Xn[4];
        if (gi < 3) {
            #pragma unroll
            for (int t = 0; t < 4; ++t)
                Xn[t] = ((const float4*)(x + (long)t * PLANE + (long)(g + 1) * 256))[lane];
        }

        // phase 2: sparse q gathers, 16 loads in flight (8 chains x depth 2)
        float4 qs0 = make_float4(0.f,0.f,0.f,0.f), qs1 = make_float4(0.f,0.f,0.f,0.f);
        float4 qs2 = make_float4(0.f,0.f,0.f,0.f), qs3 = make_float4(0.f,0.f,0.f,0.f);
        gather8(sm[0][0], sm[0][1], sm[0][2], sm[0][3],
                sm[1][0], sm[1][1], sm[1][2], sm[1][3], WqT, lane, qs0, qs1);
        gather8(sm[2][0], sm[2][1], sm[2][2], sm[2][3],
                sm[3][0], sm[3][1], sm[3][2], sm[3][3], WqT, lane, qs2, qs3);

        // phase 3: q LIF + att-token LIF (identical arithmetic to prior rounds)
        float4 vq = make_float4(0.f, 0.f, 0.f, 0.f);
        float  va = 0.f;
        unsigned attb = 0u;
        #pragma unroll
        for (int t = 0; t < 4; ++t) {
            float4 q = (t == 0) ? qs0 : (t == 1) ? qs1 : (t == 2) ? qs2 : qs3;
            vq.x = vq.x + (q.x - vq.x) * 0.5f; bool t0 = (vq.x - 1.0f) >= 0.0f; if (t0) vq.x = 0.f;
            vq.y = vq.y + (q.y - vq.y) * 0.5f; bool t1 = (vq.y - 1.0f) >= 0.0f; if (t1) vq.y = 0.f;
            vq.z = vq.z + (q.z - vq.z) * 0.5f; bool t2 = (vq.z - 1.0f) >= 0.0f; if (t2) vq.z = 0.f;
            vq.w = vq.w + (q.w - vq.w) * 0.5f; bool t3 = (vq.w - 1.0f) >= 0.0f; if (t3) vq.w = 0.f;
            unsigned long long qb0 = __ballot(t0);
            unsigned long long qb1 = __ballot(t1);
            unsigned long long qb2 = __ballot(t2);
            unsigned long long qb3 = __ballot(t3);

            int cnt = __popc((unsigned)((qb0 >> sh) & 0xFFull))
                    + __popc((unsigned)((qb1 >> sh) & 0xFFull))
                    + __popc((unsigned)((qb2 >> sh) & 0xFFull))
                    + __popc((unsigned)((qb3 >> sh) & 0xFFull));
            va = va + ((float)cnt - va) * 0.5f;
            bool a = (va - 1.0f) >= 0.0f; if (a) va = 0.f;
            attb |= (a ? 1u : 0u) << t;
        }

        bool anyatt = (__ballot(attb != 0u) != 0ull);
        if (!anyatt) {
            if (lane < 32) {
                int t = lane >> 3, wd = lane & 7;
                AM[((long)t * G + g) * 8 + wd] = 0u;
            }
        } else {
            // rare: full k path (wave-uniform)
            if (lane == 0) atomicOr(flag, 1u);
            float4 vk = make_float4(0.f, 0.f, 0.f, 0.f);
            #pragma unroll
            for (int t = 0; t < 4; ++t) {
                float k0 = 0.f, k1 = 0.f, k2 = 0.f, k3 = 0.f;
                #pragma unroll
                for (int j = 0; j < 4; ++j)
                    gather_word(sm[t][j], j, lane, WkT, k0, k1, k2, k3);
                float4 pp = ((const float4*)(pos + t * 16384 + hw * 256))[lane];
                k0 += pp.x; k1 += pp.y; k2 += pp.z; k3 += pp.w;

                vk.x = vk.x + (k0 - vk.x) * 0.5f; bool t0 = (vk.x - 1.0f) >= 0.0f; if (t0) vk.x = 0.f;
                vk.y = vk.y + (k1 - vk.y) * 0.5f; bool t1 = (vk.y - 1.0f) >= 0.0f; if (t1) vk.y = 0.f;
                vk.z = vk.z + (k2 - vk.z) * 0.5f; bool t2 = (vk.z - 1.0f) >= 0.0f; if (t2) vk.z = 0.f;
                vk.w = vk.w + (k3 - vk.w) * 0.5f; bool t3 = (vk.w - 1.0f) >= 0.0f; if (t3) vk.w = 0.f;

                bool at = ((attb >> t) & 1u) != 0u;
                unsigned long long bb[4];
                bb[0] = __ballot(t0 && at);
                bb[1] = __ballot(t1 && at);
                bb[2] = __ballot(t2 && at);
                bb[3] = __ballot(t3 && at);
                if (lane < 8) {
                    unsigned wdv = 0u;
                    #pragma unroll
                    for (int hd = 0; hd < 32; ++hd) {
                        int ls = lane * 8 + (hd >> 2);
                        wdv |= (unsigned)((bb[hd & 3] >> ls) & 1ull) << hd;
                    }
                    AM[((long)t * G + g) * 8 + lane] = wdv;
                }
            }
        }

        if (gi < 3) {
            #pragma unroll
            for (int t = 0; t < 4; ++t) X[t] = Xn[t];
        }
    }
}

// ---------------- out: flag-gated pure streaming stores ----------------
// Common case (flag==0): y = bp broadcast, attn_out = 0; no loads in the loop.
// attn_out ≡ 0 proved: x2 in {0,1}, v'=(v+x)/2 < 1 strictly (exact dyadic fp32).
// Rare case: per-row AM gather (permutation verified R0).
__global__ __launch_bounds__(256) void out_kernel(
    const unsigned* __restrict__ AM,
    const float* __restrict__ WpT,
    const float* __restrict__ bp,
    const unsigned* __restrict__ flag,
    float* __restrict__ y,
    float* __restrict__ attn_out)
{
    int lane = threadIdx.x & 63;
    int wv   = threadIdx.x >> 6;
    long wave = (long)blockIdx.x * 4 + wv;      // 0..8191 ; 32 rows/wave
    int  nh   = lane >> 3;

    float4 base = ((const float4*)bp)[lane];
    const float4 z = make_float4(0.f, 0.f, 0.f, 0.f);
    long row0 = wave * 32;

    if (*flag == 0u) {
        float4* yp = (float4*)y        + row0 * 64 + lane;
        float4* ap = (float4*)attn_out + row0 * 64 + lane;
        #pragma unroll 8
        for (int r = 0; r < 32; ++r) yp[r * 64] = base;
        #pragma unroll 8
        for (int r = 0; r < 32; ++r) ap[r * 64] = z;
        return;
    }

    // rare path
    int t2  = (int)(row0 >> 16);
    int b2  = (int)(row0 >> 6) & 1023;
    int hw2 = (int)row0 & 63;
    int srow = (b2 * 4 + (nh >> 1)) * 64 + (nh & 1) * 32 + t2 * 8 + (hw2 >> 3);
    unsigned W = AM[(long)srow * 8 + (hw2 & 7)];

    for (int r = 0; r < 32; ++r) {
        long row = row0 + r;
        unsigned Wn = 0u;
        if (r < 31) {
            long rown = row + 1;
            int t2n  = (int)(rown >> 16);
            int b2n  = (int)(rown >> 6) & 1023;
            int hw2n = (int)rown & 63;
            int srn  = (b2n * 4 + (nh >> 1)) * 64 + (nh & 1) * 32 + t2n * 8 + (hw2n >> 3);
            Wn = AM[(long)srn * 8 + (hw2n & 7)];
        }
        float4 val = base;
        if (__ballot(W != 0u) != 0ull) {
            #pragma unroll 1
            for (int n2 = 0; n2 < 8; ++n2) {
                unsigned Wx = __shfl(W, n2 * 8);
                while (Wx) {
                    int hd = __ffs(Wx) - 1;
                    Wx &= (Wx - 1);
                    float4 wl = ((const float4*)(WpT + (n2 * 32 + hd) * 256))[lane];
                    val.x += wl.x; val.y += wl.y; val.z += wl.z; val.w += wl.w;
                }
            }
        }
        ((float4*)y)[row * 64 + lane]        = val;
        ((float4*)attn_out)[row * 64 + lane] = z;
        W = Wn;
    }
}

extern "C" void kernel_launch(void* const* d_in, const int* in_sizes, int n_in,
                              void* d_out, int out_size, void* d_ws, size_t ws_size,
                              hipStream_t stream) {
    const float* x   = (const float*)d_in[0];
    const float* Wq  = (const float*)d_in[1];
    const float* Wk  = (const float*)d_in[2];
    const float* Wp  = (const float*)d_in[3];
    const float* bp  = (const float*)d_in[4];
    const float* pos = (const float*)d_in[5];

    float* y        = (float*)d_out;
    float* attn_out = y + 67108864L;

    char* ws = (char*)d_ws;
    unsigned*           AM   = (unsigned*)(ws);
    __hip_bfloat16*     WqT  = (__hip_bfloat16*)(ws + (8L << 20));
    __hip_bfloat16*     WkT  = (__hip_bfloat16*)(ws + (8L << 20) + (128L << 10));
    float*              WpT  = (float*)(ws + (8L << 20) + (256L << 10));
    unsigned*           flag = (unsigned*)(ws + (8L << 20) + (512L << 10));

    prep_kernel<<<256, 256, 0, stream>>>(Wq, Wk, Wp, WqT, WkT, WpT, flag);
    lif_qk_kernel<<<4096, 256, 0, stream>>>(x, AM, WqT, WkT, pos, flag);
    out_kernel<<<2048, 256, 0, stream>>>(AM, WpT, bp, flag, y, attn_out);
}